// Round 9
// baseline (91.715 us; speedup 1.0000x reference)
//
#include <hip/hip_runtime.h>
#include <hip/hip_bf16.h>
#include <cstdint>

#define DEV static __device__ __forceinline__

typedef float        v4f __attribute__((ext_vector_type(4)));
typedef float        v2f __attribute__((ext_vector_type(2)));
typedef short        v8s __attribute__((ext_vector_type(8)));
typedef unsigned int v4u __attribute__((ext_vector_type(4)));
typedef unsigned int v2u __attribute__((ext_vector_type(2)));

static constexpr int N_ENT = 100000;
static constexpr int BATCH = 4096;

DEV unsigned short f2bf(float f) {
    __hip_bfloat16 h = __float2bfloat16(f);
    return __builtin_bit_cast(unsigned short, h);
}
DEV unsigned int pkbf(float lo, float hi) {
    return (unsigned)f2bf(lo) | ((unsigned)f2bf(hi) << 16);
}
DEV float bflo(unsigned int w) { return __uint_as_float(w << 16); }
DEV float bfhi(unsigned int w) { return __uint_as_float(w & 0xffff0000u); }
DEV v2f up2(unsigned int w) { return (v2f){bflo(w), bfhi(w)}; }

// OCP fp8 e4m3 HW converters (gfx950) — word selector must be an immediate
template <bool HI> DEV v2f dec8(unsigned int u) {
    return __builtin_amdgcn_cvt_pk_f32_fp8((int)u, HI);
}
template <bool HI> DEV unsigned int enc8(float a, float b, unsigned int old) {
    return __builtin_amdgcn_cvt_pk_fp8_f32(a, b, (int)old, HI);
}

// async global->LDS, 16 B per lane; LDS dest = uniform base + lane*16
DEV void glds16(const void* g, void* l) {
    __builtin_amdgcn_global_load_lds(
        (const __attribute__((address_space(1))) unsigned int*)g,
        (__attribute__((address_space(3))) unsigned int*)l, 16, 0, 0);
}

// ---------------- K0: R1f = fp8(rel @ W1[64:]); W2p/W1p packed MFMA fragment layout
__global__ void k0_prep(const float* __restrict__ rel, const float* __restrict__ W1,
                        const float* __restrict__ W2,
                        unsigned char* __restrict__ R1f, unsigned short* __restrict__ W2p,
                        unsigned short* __restrict__ W1p)
{
    const int gid = blockIdx.x * 256 + threadIdx.x;
    if (gid < 1024) {
        const int r = gid >> 5, jp = gid & 31;
        float d0 = 0.f, d1 = 0.f;
        #pragma unroll 8
        for (int k = 0; k < 64; ++k) {
            const float rv = rel[r * 64 + k];
            d0 += rv * W1[(64 + k) * 64 + 2 * jp];
            d1 += rv * W1[(64 + k) * 64 + 2 * jp + 1];
        }
        const unsigned int u = enc8<false>(d0, d1, 0u);
        ((unsigned short*)R1f)[r * 32 + jp] = (unsigned short)(u & 0xffffu);
    } else if (gid < 1024 + 4096) {
        // Wp[((kk*4+tn)*64 + l)*8 + i] = bf16( W[(32kk + 8*(l>>4) + i)][16tn + (l&15)] )
        const int f = gid - 1024;
        const int i = f & 7, l = (f >> 3) & 63;
        const int tn = (f >> 9) & 3, kk = f >> 11;
        W2p[f] = f2bf(W2[(32 * kk + 8 * (l >> 4) + i) * 64 + 16 * tn + (l & 15)]);
    } else if (gid < 1024 + 8192) {
        const int f = gid - 5120;
        const int i = f & 7, l = (f >> 3) & 63;
        const int tn = (f >> 9) & 3, kk = f >> 11;
        W1p[f] = f2bf(W1[(32 * kk + 8 * (l >> 4) + i) * 64 + 16 * tn + (l & 15)]);
    }
}

// ---------------- K1: transposed MFMA: E1f[e][j] fp8 = (emb @ W1[:64]); E0 = bf16(emb)
__global__ void __launch_bounds__(256) k1_e1(const float* __restrict__ emb,
                                             const unsigned short* __restrict__ W1p,
                                             unsigned char* __restrict__ E1f,
                                             unsigned short* __restrict__ E0)
{
    const int lane = threadIdx.x & 63;
    const int q = lane & 15, g = lane >> 4;
    const int wid = blockIdx.x * 4 + (threadIdx.x >> 6);
    const int e0 = wid * 16;
    if (e0 >= N_ENT) return;

    v8s bf[2];
    #pragma unroll
    for (int kk = 0; kk < 2; ++kk) {
        const float* p = emb + (size_t)(e0 + q) * 64 + 32 * kk + 8 * g;
        const v4f x = *(const v4f*)p;
        const v4f y = *(const v4f*)(p + 4);
        v4u pk;
        pk[0] = pkbf(x[0], x[1]); pk[1] = pkbf(x[2], x[3]);
        pk[2] = pkbf(y[0], y[1]); pk[3] = pkbf(y[2], y[3]);
        bf[kk] = __builtin_bit_cast(v8s, pk);
        *(v4u*)(E0 + (size_t)(e0 + q) * 64 + 32 * kk + 8 * g) = pk;
    }

    // D = W1^T-block * emb-block: lane(q,g) reg i = E1[e0+q][16*tile + 4g + i]
    v4f acc[4];
    #pragma unroll
    for (int tile = 0; tile < 4; ++tile) acc[tile] = (v4f){0.f, 0.f, 0.f, 0.f};
    #pragma unroll
    for (int kk = 0; kk < 2; ++kk)
        #pragma unroll
        for (int tile = 0; tile < 4; ++tile) {
            const v8s w1f = *(const v8s*)(W1p + ((kk * 4 + tile) * 64 + lane) * 8);
            acc[tile] = __builtin_amdgcn_mfma_f32_16x16x32_bf16(w1f, bf[kk], acc[tile], 0, 0, 0);
        }
    #pragma unroll
    for (int tile = 0; tile < 4; ++tile) {
        unsigned int u = enc8<false>(acc[tile][0], acc[tile][1], 0u);
        u = enc8<true>(acc[tile][2], acc[tile][3], u);
        *(unsigned int*)(E1f + (size_t)(e0 + q) * 64 + 16 * tile + 4 * g) = u;
    }
}

// ---------------- K2: fused attention + means + dot + sigmoid (fp8 h-path, LDS R1)
__global__ void __launch_bounds__(256) k2_fused(
    const int* __restrict__ items,
    const int* __restrict__ user_h, const int* __restrict__ user_r, const int* __restrict__ user_t,
    const int* __restrict__ item_h, const int* __restrict__ item_r, const int* __restrict__ item_t,
    const float* __restrict__ emb, const unsigned short* __restrict__ E0,
    const unsigned char* __restrict__ E1f,
    const unsigned char* __restrict__ R1f, const unsigned short* __restrict__ W2p,
    const float* __restrict__ W3, float* __restrict__ out)
{
    __shared__ float ws_w[4][64];   // softmax weights (wave-private exchange, no barrier)
    __shared__ float att_s[4][64];  // per-combo attention output
    __shared__ float mp[4][64];     // per-wave mean partials
    __shared__ __align__(16) unsigned char r1s[2048];     // fp8 R1 (32 rows x 64 B)
    __shared__ __align__(16) unsigned char e0s[4][8192];  // staged t-rows  (8 KiB/wave)
    __shared__ __align__(16) unsigned char m0s[4][4096];  // staged mean rows (4 KiB/wave)

    const int lane  = threadIdx.x & 63;
    const int b     = blockIdx.x;
    const int combo = threadIdx.x >> 6;        // 0:uL0 1:uL1 2:iL0 3:iL1
    const int layer = combo & 1;
    const int side  = combo >> 1, half = combo & 1;
    const int* Hp; const int* Rp; const int* Tp;
    if (combo < 2) { Hp = user_h; Rp = user_r; Tp = user_t; }
    else           { Hp = item_h; Rp = item_r; Tp = item_t; }
    const int base = (layer * BATCH + b) * 64;
    const int* H0p = (side ? item_h : user_h) + b * 64;   // layer-0 heads for mean

    const int q = lane & 15, g = lane >> 4;
    const int sub = lane & 7, grp = lane >> 3;

    // ---- 1. indices + hot weights (all issued before the staging barrier)
    int hidx[4], ridx[4];
    #pragma unroll
    for (int tm = 0; tm < 4; ++tm) {
        hidx[tm] = Hp[base + 16 * tm + q];
        ridx[tm] = Rp[base + 16 * tm + q];
    }
    const int tv = Tp[base + lane];
    int midx[4];
    #pragma unroll
    for (int it = 0; it < 4; ++it) midx[it] = H0p[32 * half + 8 * it + grp];
    float w3v[4];
    #pragma unroll
    for (int tn = 0; tn < 4; ++tn) w3v[tn] = W3[16 * tn + q];
    v8s bfr[2][4];
    #pragma unroll
    for (int kk = 0; kk < 2; ++kk)
        #pragma unroll
        for (int tn = 0; tn < 4; ++tn)
            bfr[kk][tn] = *(const v8s*)(W2p + ((kk * 4 + tn) * 64 + lane) * 8);

    // ---- 2. stage R1f (2 KB) into LDS; one barrier at kernel start
    if (threadIdx.x < 128) {
        const v4u t = *(const v4u*)(R1f + threadIdx.x * 16);
        *(v4u*)&r1s[threadIdx.x * 16] = t;
    }
    __syncthreads();

    // ---- 3. fp8 E1 gathers (8 B/lane; one 64 B line per row)
    v2u ev[4][2];
    #pragma unroll
    for (int tm = 0; tm < 4; ++tm)
        #pragma unroll
        for (int kk = 0; kk < 2; ++kk)
            ev[tm][kk] = *(const v2u*)(E1f + (size_t)hidx[tm] * 64 + 32 * kk + 8 * g);

    // ---- 4. async LDS staging for post-softmax consumers
    #pragma unroll
    for (int it = 0; it < 8; ++it) {
        const int tr = __shfl(tv, 8 * it + grp);
        glds16(E0 + (size_t)tr * 64 + sub * 8, &e0s[combo][it * 1024]);
    }
    #pragma unroll
    for (int it = 0; it < 4; ++it)
        glds16(E0 + (size_t)midx[it] * 64 + sub * 8, &m0s[combo][it * 1024]);
    __builtin_amdgcn_sched_barrier(0);   // pin issue point; no data wait implied

    // ---- 5. R1 fragments from LDS (off the VMEM port)
    v2u rv[4][2];
    #pragma unroll
    for (int tm = 0; tm < 4; ++tm)
        #pragma unroll
        for (int kk = 0; kk < 2; ++kk)
            rv[tm][kk] = *(const v2u*)&r1s[ridx[tm] * 64 + 32 * kk + 8 * g];

    // ---- 6. MFMA: a2 = relu(relu(E1h + R1r) @ W2); logits p
    float p[4][4];
    #pragma unroll
    for (int tm = 0; tm < 4; ++tm) {
        v4f a4[4];
        #pragma unroll
        for (int tn = 0; tn < 4; ++tn) a4[tn] = (v4f){0.f, 0.f, 0.f, 0.f};
        #pragma unroll
        for (int kk = 0; kk < 2; ++kk) {
            const v2u e8 = ev[tm][kk], r8 = rv[tm][kk];
            v2f a01 = dec8<false>(e8[0]) + dec8<false>(r8[0]);
            v2f a23 = dec8<true>(e8[0])  + dec8<true>(r8[0]);
            v2f a45 = dec8<false>(e8[1]) + dec8<false>(r8[1]);
            v2f a67 = dec8<true>(e8[1])  + dec8<true>(r8[1]);
            v4u afu;
            afu[0] = pkbf(fmaxf(a01[0], 0.f), fmaxf(a01[1], 0.f));
            afu[1] = pkbf(fmaxf(a23[0], 0.f), fmaxf(a23[1], 0.f));
            afu[2] = pkbf(fmaxf(a45[0], 0.f), fmaxf(a45[1], 0.f));
            afu[3] = pkbf(fmaxf(a67[0], 0.f), fmaxf(a67[1], 0.f));
            const v8s af = __builtin_bit_cast(v8s, afu);
            #pragma unroll
            for (int tn = 0; tn < 4; ++tn)
                a4[tn] = __builtin_amdgcn_mfma_f32_16x16x32_bf16(af, bfr[kk][tn], a4[tn], 0, 0, 0);
        }
        #pragma unroll
        for (int i = 0; i < 4; ++i) {
            float s = 0.f;
            #pragma unroll
            for (int tn = 0; tn < 4; ++tn)
                s += fmaxf(a4[tn][i], 0.f) * w3v[tn];
            p[tm][i] = s;
        }
    }
    #pragma unroll
    for (int m = 1; m <= 8; m <<= 1)
        #pragma unroll
        for (int tm = 0; tm < 4; ++tm)
            #pragma unroll
            for (int i = 0; i < 4; ++i)
                p[tm][i] += __shfl_xor(p[tm][i], m);

    // ---- 7. sigmoid -> exp -> softmax sum (logits in [0,1], no max-shift needed)
    float ee[4][4];
    float sloc = 0.f;
    #pragma unroll
    for (int tm = 0; tm < 4; ++tm)
        #pragma unroll
        for (int i = 0; i < 4; ++i) {
            const float sg = 1.f / (1.f + __expf(-p[tm][i]));
            const float ex = __expf(sg);
            ee[tm][i] = ex;
            sloc += ex;
        }
    sloc += __shfl_xor(sloc, 16);
    sloc += __shfl_xor(sloc, 32);
    const float rS = 1.f / sloc;

    // wave-private weight exchange through LDS (same wave writes & reads: no barrier)
    if (q == 0) {
        #pragma unroll
        for (int tm = 0; tm < 4; ++tm) {
            v4f wv;
            #pragma unroll
            for (int i = 0; i < 4; ++i) wv[i] = ee[tm][i] * rS;
            *(v4f*)&ws_w[combo][16 * tm + 4 * g] = wv;
        }
    }

    // ---- 8. staged gathers have had the whole MFMA+softmax phase to land
    asm volatile("s_waitcnt vmcnt(0)" ::: "memory");
    __builtin_amdgcn_sched_barrier(0);

    // ---- 9. weighted t-sum + hop-0 means from staged LDS (packed f32 math)
    v2f a2[4], m2[4];
    #pragma unroll
    for (int c = 0; c < 4; ++c) { a2[c] = (v2f){0.f, 0.f}; m2[c] = (v2f){0.f, 0.f}; }
    #pragma unroll
    for (int it = 0; it < 8; ++it) {
        const float w = ws_w[combo][8 * it + grp];
        const v2f wv = (v2f){w, w};
        const v4u e = *(const v4u*)&e0s[combo][it * 1024 + lane * 16];
        #pragma unroll
        for (int c = 0; c < 4; ++c) a2[c] += wv * up2(e[c]);
    }
    #pragma unroll
    for (int it = 0; it < 4; ++it) {
        const v4u e = *(const v4u*)&m0s[combo][it * 1024 + lane * 16];
        #pragma unroll
        for (int c = 0; c < 4; ++c) m2[c] += up2(e[c]);
    }
    #pragma unroll
    for (int m = 8; m <= 32; m <<= 1)
        #pragma unroll
        for (int c = 0; c < 4; ++c) {
            a2[c][0] += __shfl_xor(a2[c][0], m);
            a2[c][1] += __shfl_xor(a2[c][1], m);
            m2[c][0] += __shfl_xor(m2[c][0], m);
            m2[c][1] += __shfl_xor(m2[c][1], m);
        }
    if (lane < 8) {
        #pragma unroll
        for (int c = 0; c < 4; ++c) {
            att_s[combo][lane * 8 + 2 * c]     = a2[c][0];
            att_s[combo][lane * 8 + 2 * c + 1] = a2[c][1];
            mp[combo][lane * 8 + 2 * c]        = m2[c][0];
            mp[combo][lane * 8 + 2 * c + 1]    = m2[c][1];
        }
    }
    __syncthreads();

    // ---- 10. final combine + dot + sigmoid (wave 0)
    if (threadIdx.x < 64) {
        const int j = lane;
        const float itemv = emb[(size_t)items[b] * 64 + j];
        const float eu = att_s[0][j] + att_s[1][j] + (mp[0][j] + mp[1][j]) * (1.f / 64.f);
        const float evv = itemv + att_s[2][j] + att_s[3][j]
                        + (mp[2][j] + mp[3][j]) * (1.f / 64.f);
        float d = eu * evv;
        #pragma unroll
        for (int m = 1; m <= 32; m <<= 1) d += __shfl_xor(d, m);
        if (lane == 0) out[b] = 1.f / (1.f + __expf(-d));
    }
}

extern "C" void kernel_launch(void* const* d_in, const int* in_sizes, int n_in,
                              void* d_out, int out_size, void* d_ws, size_t ws_size,
                              hipStream_t stream)
{
    const int*   items  = (const int*)d_in[0];
    const int*   user_h = (const int*)d_in[1];
    const int*   user_r = (const int*)d_in[2];
    const int*   user_t = (const int*)d_in[3];
    const int*   item_h = (const int*)d_in[4];
    const int*   item_r = (const int*)d_in[5];
    const int*   item_t = (const int*)d_in[6];
    const float* emb    = (const float*)d_in[7];
    const float* rel    = (const float*)d_in[8];
    const float* W1     = (const float*)d_in[9];
    const float* W2     = (const float*)d_in[10];
    const float* W3     = (const float*)d_in[11];
    float* out = (float*)d_out;

    char* ws = (char*)d_ws;
    const size_t e0b = (size_t)N_ENT * 64 * 2;   // 12.8 MB bf16 table
    const size_t e1b = (size_t)N_ENT * 64;       // 6.4 MB fp8 table
    unsigned short* E0  = (unsigned short*)ws;
    unsigned char*  E1f = (unsigned char*)(ws + e0b);
    unsigned char*  R1f = (unsigned char*)(ws + e0b + e1b);
    unsigned short* W2p = (unsigned short*)(ws + e0b + e1b + 2048);
    unsigned short* W1p = (unsigned short*)(ws + e0b + e1b + 2048 + 8192);

    hipLaunchKernelGGL(k0_prep, dim3(36), dim3(256), 0, stream, rel, W1, W2, R1f, W2p, W1p);
    hipLaunchKernelGGL(k1_e1, dim3((6250 + 3) / 4), dim3(256), 0, stream, emb, W1p, E1f, E0);
    hipLaunchKernelGGL(k2_fused, dim3(BATCH), dim3(256), 0, stream,
                       items, user_h, user_r, user_t, item_h, item_r, item_t,
                       emb, E0, E1f, R1f, W2p, W3, out);
}